// Round 6
// baseline (420.513 us; speedup 1.0000x reference)
//
#include <hip/hip_runtime.h>

// ElmanRNN via MFMA, v2: BATCH=4096, SEQ=512, IN=2, HID=128, OUT=1
// h_{t+1} = tanh(h_t @ Wh^T + x_t @ Wx^T + b);  out = h_S @ Who^T + b_ho
//
// R4 (430us) analysis: 2016 cy/step/CU; VALU 59% busy (tanh + manual hi/lo
// bf16 split + 2B scatter stores), 3.37e7 LDS bank conflicts (2B stores:
// row-swizzle keys collide pairwise + same-word 2B writes). MFMA only ~6%.
//
// v2: h stored as ONE interleaved (hhi,hlo) plane = ext-K of 256. Two MFMA
// passes over the SAME A-fragments with duplicated-pair B operands:
//   P1: B_ext = (Whi,Whi)  ->  Whi*(hhi+hlo)
//   P2: B_ext = (Wlo,Wlo)  ->  Wlo*(hhi+hlo)
// Sum = (Whi+Wlo)*(hhi+hlo): BETTER precision than R4's 3-product form.
// Same LDS read volume (8 b128/lane), MFMA 12->16 (cheap), and the write
// side becomes 4x 4B stores built by v_cvt_pk_bf16_f32 (4 VALU per row
// instead of ~12 bit-twiddling ops). Duplicated-pair B makes the kernel
// immune to cvt_pk's half ordering. All swizzled LDS offsets hoisted.

constexpr int BATCH   = 4096;
constexpr int SEQ     = 512;
constexpr int INP     = 2;
constexpr int HID     = 128;
constexpr int BM      = 16;    // batch rows per block
constexpr int THREADS = 512;   // 8 waves, 1 block/CU, 2 waves/SIMD
constexpr int XCHUNK  = 128;   // time steps of x staged per chunk
constexpr int XROW    = XCHUNK * INP + 4;   // 260 floats: pad kills bank collisions

typedef short bf16x8 __attribute__((ext_vector_type(8)));
typedef float f32x4  __attribute__((ext_vector_type(4)));
typedef unsigned int u32x4 __attribute__((ext_vector_type(4)));

__device__ inline unsigned cvt_pk_bf16(float a, float b) {
    unsigned r;
    asm("v_cvt_pk_bf16_f32 %0, %1, %2" : "=v"(r) : "v"(a), "v"(b));
    return r;
}

__global__ __launch_bounds__(THREADS, 2)
void elman_mfma2(const float* __restrict__ x,
                 const float* __restrict__ W_ih,
                 const float* __restrict__ b_ih,
                 const float* __restrict__ W_ho,
                 const float* __restrict__ b_ho,
                 float* __restrict__ out)
{
    // interleaved (hhi,hlo) plane: [buf][row 16][ext 256] bf16, 512 B/row
    __shared__ unsigned short hlds[2][BM][2 * HID];   // 16 KB
    __shared__ float xs[BM][XROW];                    // 16.6 KB
    __shared__ float red[BM][8];

    const int tid  = threadIdx.x;
    const int lane = tid & 63;
    const int w    = tid >> 6;        // wave id -> j-tile [16w, 16w+16)
    const int l15  = lane & 15;
    const int g    = lane >> 4;       // 0..3
    const int j    = w * 16 + l15;    // output column this lane owns
    const int B0   = blockIdx.x * BM;

    // ---- stationary B fragments: duplicated-pair (Whi,Whi) and (Wlo,Wlo) ----
    // ext element e = kt*32 + g*8 + i maps to k = e>>1 = kt*16 + g*4 + (i>>1):
    // frag word m (=i>>1) = duplicated bf16 pair of W[j][kt*16+g*4+m].
    bf16x8 Bhi[8], Blo[8];
    {
        const float* Wrow = W_ih + (size_t)j * (INP + HID) + INP;
        #pragma unroll
        for (int kt = 0; kt < 8; ++kt) {
            const float4 wv = *reinterpret_cast<const float4*>(Wrow + kt * 16 + g * 4);
            const float wm[4] = {wv.x, wv.y, wv.z, wv.w};
            u32x4 hi, lo;
            #pragma unroll
            for (int m = 0; m < 4; ++m) {
                const unsigned c1 = cvt_pk_bf16(wm[m], wm[m]);   // (bf(w), bf(w))
                const float whf = __uint_as_float(c1 << 16);     // bf(w) as f32
                const float wl  = wm[m] - whf;
                hi[m] = c1;
                lo[m] = cvt_pk_bf16(wl, wl);                     // (bf(wl), bf(wl))
            }
            Bhi[kt] = __builtin_bit_cast(bf16x8, hi);
            Blo[kt] = __builtin_bit_cast(bf16x8, lo);
        }
    }
    const float* Wrow0 = W_ih + (size_t)j * (INP + HID);
    const float wx0 = Wrow0[0];
    const float wx1 = Wrow0[1];
    const float bj  = b_ih[j];

    // ---- hoisted swizzled LDS offsets ----
    // read: row l15, ext-tile kt -> byte l15*512 + ((kt*64+g*16) ^ key(l15))
    // write: row rr=g*4+i, col-pair j -> byte rr*512 + ((4j) ^ key(rr))
    int roff[8];
    #pragma unroll
    for (int kt = 0; kt < 8; ++kt)
        roff[kt] = l15 * 512 + ((kt * 64 + g * 16) ^ ((l15 & 7) << 4));
    int woff[4];
    #pragma unroll
    for (int i = 0; i < 4; ++i) {
        const int rr = g * 4 + i;
        woff[i] = rr * 512 + ((4 * j) ^ ((rr & 7) << 4));
    }

    // ---- h0 = 0 (buf 0 = first 8 KB = 512 float4) ----
    reinterpret_cast<float4*>(hlds)[tid] = float4{0.f, 0.f, 0.f, 0.f};

    // ---- stage x chunk 0 ----
    const int sr = tid >> 5;            // 0..15
    const int sc = (tid & 31) * 4;      // 0..124
    {
        const float* src = x + (size_t)(B0 + sr) * (SEQ * INP) + sc;
        *reinterpret_cast<float4*>(&xs[sr][sc])       = *reinterpret_cast<const float4*>(src);
        *reinterpret_cast<float4*>(&xs[sr][sc + 128]) = *reinterpret_cast<const float4*>(src + 128);
    }
    __syncthreads();

    const char* hb0 = (const char*)&hlds[0][0][0];
    const char* hb1 = (const char*)&hlds[1][0][0];
    int p = 0;
    float hv[4] = {0.f, 0.f, 0.f, 0.f};

    #pragma unroll 1
    for (int t = 0; t < SEQ; ++t) {
        const int tt = t & (XCHUNK - 1);
        if (t && tt == 0) {
            // end-of-step barrier of t-1 guarantees xs no longer read
            const float* src = x + (size_t)(B0 + sr) * (SEQ * INP)
                                 + (size_t)(t >> 7) * (XCHUNK * INP) + sc;
            *reinterpret_cast<float4*>(&xs[sr][sc])       = *reinterpret_cast<const float4*>(src);
            *reinterpret_cast<float4*>(&xs[sr][sc + 128]) = *reinterpret_cast<const float4*>(src + 128);
            __syncthreads();
        }

        // ---- A fragments: full interleaved row of h (8 x b128) ----
        const char* hp = p ? hb1 : hb0;
        bf16x8 A[8];
        #pragma unroll
        for (int kt = 0; kt < 8; ++kt)
            A[kt] = *reinterpret_cast<const bf16x8*>(hp + roff[kt]);

        // ---- two-product compensated GEMM over ext-K=256 ----
        f32x4 a0 = {0.f, 0.f, 0.f, 0.f};
        f32x4 a1 = {0.f, 0.f, 0.f, 0.f};
        #pragma unroll
        for (int kt = 0; kt < 8; ++kt) {
            a0 = __builtin_amdgcn_mfma_f32_16x16x32_bf16(A[kt], Bhi[kt], a0, 0, 0, 0);
            a1 = __builtin_amdgcn_mfma_f32_16x16x32_bf16(A[kt], Blo[kt], a1, 0, 0, 0);
        }

        // ---- x-term + bias + tanh + cvt_pk split + 4B packed store ----
        char* wp = (char*)(p ? hb0 : hb1);
        #pragma unroll
        for (int i = 0; i < 4; ++i) {
            const int rr = g * 4 + i;                       // D-row (batch row)
            const float2 xv = *reinterpret_cast<const float2*>(&xs[rr][2 * tt]);
            const float acc = (a0[i] + a1[i])
                            + fmaf(wx0, xv.x, fmaf(wx1, xv.y, bj));
            const float e = __expf(acc + acc);
            const float h = 1.0f - __fdividef(2.0f, e + 1.0f);   // tanh(acc)
            hv[i] = h;
            const unsigned c1  = cvt_pk_bf16(h, h);          // (bf(h), bf(h))
            const float    hbf = __uint_as_float(c1 << 16);  // bf(h) as f32
            const float    lo  = h - hbf;
            const unsigned c2  = cvt_pk_bf16(h, lo);         // (bf(h), bf(lo))
            *reinterpret_cast<unsigned*>(wp + woff[i]) = c2;
        }
        __syncthreads();
        p ^= 1;
    }

    // ---- epilogue: out[r] = sum_j Who[j]*h[r][j] + b_ho ----
    const float who = W_ho[j];
    float pr[4];
    #pragma unroll
    for (int i = 0; i < 4; ++i) {
        float v = who * hv[i];
        v += __shfl_xor(v, 1);
        v += __shfl_xor(v, 2);
        v += __shfl_xor(v, 4);
        v += __shfl_xor(v, 8);     // 16-lane j-reduction within wave's tile
        pr[i] = v;
    }
    if (l15 == 0) {
        #pragma unroll
        for (int i = 0; i < 4; ++i) red[g * 4 + i][w] = pr[i];
    }
    __syncthreads();
    if (tid < BM) {
        float s = b_ho[0];
        #pragma unroll
        for (int q = 0; q < 8; ++q) s += red[tid][q];
        out[B0 + tid] = s;
    }
}

extern "C" void kernel_launch(void* const* d_in, const int* in_sizes, int n_in,
                              void* d_out, int out_size, void* d_ws, size_t ws_size,
                              hipStream_t stream)
{
    (void)in_sizes; (void)n_in; (void)out_size; (void)d_ws; (void)ws_size;
    const float* x    = (const float*)d_in[0];
    const float* W_ih = (const float*)d_in[1];
    const float* b_ih = (const float*)d_in[2];
    const float* W_ho = (const float*)d_in[3];
    const float* b_ho = (const float*)d_in[4];
    float* out = (float*)d_out;

    dim3 grid(BATCH / BM);     // 256 blocks = 1 per CU
    dim3 block(THREADS);
    elman_mfma2<<<grid, block, 0, stream>>>(x, W_ih, b_ih, W_ho, b_ho, out);
}

// Round 7
// 412.669 us; speedup vs baseline: 1.0190x; 1.0190x over previous
//
#include <hip/hip_runtime.h>

// ElmanRNN via MFMA, v3: BATCH=4096, SEQ=512, IN=2, HID=128, OUT=1
// h_{t+1} = tanh(h_t @ Wh^T + x_t @ Wx^T + b);  out = h_S @ Who^T + b_ho
//
// R5 budget analysis (2000 cy/step/CU): A-read broadcast redundancy dominates
// — 8 waves each read the full 8 KB h-tile (64 KB/step = 512 cy @128 B/cy
// + 33% conflicts), plus 2048 tanh/step/CU (16 trans/lane; ~512 cy/SIMD at
// quarter-rate with 2 waves), plus MFMA dep chains (278 cy).
//
// v3: 4 waves x 32 cols (256 thr, grid 256 = 1 block/CU, 1 wave/SIMD).
//  - A-read volume halved: 4 waves x 8 KB = 32 KB/step; A-frags read ONCE,
//    reused for both 16-col tiles.
//  - per-SIMD trans pressure halved (1 wave x 16 trans).
//  - 32 MFMA in 4 independent chains (issue 160 cy, dep latency hidden).
//  - B-frags: 2 tiles x (8 hi + 8 lo) = 32 frags = 128 reg-equivalents;
//    parks in gfx950 unified VGPR/AGPR file (R5: VGPR_Count=60 with a
//    64-reg B file proves the compiler does this).
// h storage unchanged from R5: interleaved (hhi,hlo) ext-K=256 plane,
// duplicated-pair B fragments, XOR swizzle byte ^= (row&7)<<4.

constexpr int BATCH   = 4096;
constexpr int SEQ     = 512;
constexpr int INP     = 2;
constexpr int HID     = 128;
constexpr int BM      = 16;    // batch rows per block
constexpr int THREADS = 256;   // 4 waves, 1 block/CU, 1 wave/SIMD
constexpr int XCHUNK  = 128;   // time steps of x staged per chunk
constexpr int XROW    = XCHUNK * INP + 4;   // 260 floats: pad for bank spread

typedef short bf16x8 __attribute__((ext_vector_type(8)));
typedef float f32x4  __attribute__((ext_vector_type(4)));
typedef unsigned int u32x4 __attribute__((ext_vector_type(4)));

__device__ inline unsigned cvt_pk_bf16(float a, float b) {
    unsigned r;
    asm("v_cvt_pk_bf16_f32 %0, %1, %2" : "=v"(r) : "v"(a), "v"(b));
    return r;
}

__global__ __launch_bounds__(THREADS, 1)
void elman_mfma3(const float* __restrict__ x,
                 const float* __restrict__ W_ih,
                 const float* __restrict__ b_ih,
                 const float* __restrict__ W_ho,
                 const float* __restrict__ b_ho,
                 float* __restrict__ out)
{
    // interleaved (hhi,hlo) plane: [buf][row 16][ext 256] bf16, 512 B/row
    __shared__ unsigned short hlds[2][BM][2 * HID];   // 16 KB
    __shared__ float xs[BM][XROW];                    // 16.6 KB
    __shared__ float red[BM][8];

    const int tid  = threadIdx.x;
    const int lane = tid & 63;
    const int w    = tid >> 6;        // wave id 0..3 -> j range [32w, 32w+32)
    const int l15  = lane & 15;
    const int g    = lane >> 4;       // 0..3
    const int B0   = blockIdx.x * BM;

    // ---- stationary B fragments for both col-tiles (duplicated-pair) ----
    // tile c covers cols [32w+16c, 32w+16c+16); lane owns col j_c.
    int jc[2];
    jc[0] = w * 32 + l15;
    jc[1] = w * 32 + 16 + l15;
    bf16x8 Bhi[2][8], Blo[2][8];
    float wx0[2], wx1[2], bj[2], who[2];
    #pragma unroll
    for (int c = 0; c < 2; ++c) {
        const float* Wrow = W_ih + (size_t)jc[c] * (INP + HID);
        wx0[c] = Wrow[0];
        wx1[c] = Wrow[1];
        bj[c]  = b_ih[jc[c]];
        who[c] = W_ho[jc[c]];
        #pragma unroll
        for (int kt = 0; kt < 8; ++kt) {
            const float4 wv = *reinterpret_cast<const float4*>(Wrow + INP + kt * 16 + g * 4);
            const float wm[4] = {wv.x, wv.y, wv.z, wv.w};
            u32x4 hi, lo;
            #pragma unroll
            for (int m = 0; m < 4; ++m) {
                const unsigned c1 = cvt_pk_bf16(wm[m], wm[m]);   // (bf(w), bf(w))
                const float whf = __uint_as_float(c1 << 16);
                const float wl  = wm[m] - whf;
                hi[m] = c1;
                lo[m] = cvt_pk_bf16(wl, wl);
            }
            Bhi[c][kt] = __builtin_bit_cast(bf16x8, hi);
            Blo[c][kt] = __builtin_bit_cast(bf16x8, lo);
        }
    }

    // ---- hoisted swizzled LDS offsets ----
    int roff[8];
    #pragma unroll
    for (int kt = 0; kt < 8; ++kt)
        roff[kt] = l15 * 512 + ((kt * 64 + g * 16) ^ ((l15 & 7) << 4));
    int woff[2][4];
    #pragma unroll
    for (int c = 0; c < 2; ++c)
        #pragma unroll
        for (int i = 0; i < 4; ++i) {
            const int rr = g * 4 + i;
            woff[c][i] = rr * 512 + ((4 * jc[c]) ^ ((rr & 7) << 4));
        }

    // ---- h0 = 0 (16 KB = 1024 float4, 256 threads x 4) ----
    #pragma unroll
    for (int q = 0; q < 4; ++q)
        reinterpret_cast<float4*>(hlds)[tid + 256 * q] = float4{0.f, 0.f, 0.f, 0.f};

    // ---- stage x chunk 0 (rows sr, sr+8; cols sc, sc+128: coalesced) ----
    const int sr = tid >> 5;            // 0..7
    const int sc = (tid & 31) * 4;      // 0..124
    {
        const float* s0 = x + (size_t)(B0 + sr) * (SEQ * INP) + sc;
        const float* s1 = x + (size_t)(B0 + sr + 8) * (SEQ * INP) + sc;
        *reinterpret_cast<float4*>(&xs[sr][sc])           = *reinterpret_cast<const float4*>(s0);
        *reinterpret_cast<float4*>(&xs[sr][sc + 128])     = *reinterpret_cast<const float4*>(s0 + 128);
        *reinterpret_cast<float4*>(&xs[sr + 8][sc])       = *reinterpret_cast<const float4*>(s1);
        *reinterpret_cast<float4*>(&xs[sr + 8][sc + 128]) = *reinterpret_cast<const float4*>(s1 + 128);
    }
    __syncthreads();

    const char* hb0 = (const char*)&hlds[0][0][0];
    const char* hb1 = (const char*)&hlds[1][0][0];
    int p = 0;
    float hv[2][4];                     // final-step h (epilogue)
    #pragma unroll
    for (int c = 0; c < 2; ++c)
        #pragma unroll
        for (int i = 0; i < 4; ++i) hv[c][i] = 0.f;

    #pragma unroll 1
    for (int t = 0; t < SEQ; ++t) {
        const int tt = t & (XCHUNK - 1);
        if (t && tt == 0) {
            const size_t cb = (size_t)(t >> 7) * (XCHUNK * INP);
            const float* s0 = x + (size_t)(B0 + sr) * (SEQ * INP) + cb + sc;
            const float* s1 = x + (size_t)(B0 + sr + 8) * (SEQ * INP) + cb + sc;
            *reinterpret_cast<float4*>(&xs[sr][sc])           = *reinterpret_cast<const float4*>(s0);
            *reinterpret_cast<float4*>(&xs[sr][sc + 128])     = *reinterpret_cast<const float4*>(s0 + 128);
            *reinterpret_cast<float4*>(&xs[sr + 8][sc])       = *reinterpret_cast<const float4*>(s1);
            *reinterpret_cast<float4*>(&xs[sr + 8][sc + 128]) = *reinterpret_cast<const float4*>(s1 + 128);
            __syncthreads();
        }

        // ---- A fragments: full interleaved h row-slice (8 x b128), shared
        //      by both col-tiles ----
        const char* hp = p ? hb1 : hb0;
        bf16x8 A[8];
        #pragma unroll
        for (int kt = 0; kt < 8; ++kt)
            A[kt] = *reinterpret_cast<const bf16x8*>(hp + roff[kt]);

        // ---- 4 independent MFMA chains over ext-K=256 ----
        f32x4 a00 = {0.f, 0.f, 0.f, 0.f};   // tile 0, Bhi
        f32x4 a10 = {0.f, 0.f, 0.f, 0.f};   // tile 0, Blo
        f32x4 a01 = {0.f, 0.f, 0.f, 0.f};   // tile 1, Bhi
        f32x4 a11 = {0.f, 0.f, 0.f, 0.f};   // tile 1, Blo
        #pragma unroll
        for (int kt = 0; kt < 8; ++kt) {
            a00 = __builtin_amdgcn_mfma_f32_16x16x32_bf16(A[kt], Bhi[0][kt], a00, 0, 0, 0);
            a10 = __builtin_amdgcn_mfma_f32_16x16x32_bf16(A[kt], Blo[0][kt], a10, 0, 0, 0);
            a01 = __builtin_amdgcn_mfma_f32_16x16x32_bf16(A[kt], Bhi[1][kt], a01, 0, 0, 0);
            a11 = __builtin_amdgcn_mfma_f32_16x16x32_bf16(A[kt], Blo[1][kt], a11, 0, 0, 0);
        }

        // ---- x-term (4 rows, shared by both tiles) ----
        float2 xv[4];
        #pragma unroll
        for (int i = 0; i < 4; ++i)
            xv[i] = *reinterpret_cast<const float2*>(&xs[g * 4 + i][2 * tt]);

        // ---- bias + tanh + cvt_pk split + 4B packed store (8 outputs) ----
        char* wp = (char*)(p ? hb0 : hb1);
        #pragma unroll
        for (int c = 0; c < 2; ++c) {
            const f32x4 ah = c ? a01 : a00;
            const f32x4 al = c ? a11 : a10;
            #pragma unroll
            for (int i = 0; i < 4; ++i) {
                const float acc = (ah[i] + al[i])
                                + fmaf(wx0[c], xv[i].x, fmaf(wx1[c], xv[i].y, bj[c]));
                const float e = __expf(acc + acc);
                const float h = 1.0f - __fdividef(2.0f, e + 1.0f);   // tanh
                hv[c][i] = h;
                const unsigned c1  = cvt_pk_bf16(h, h);
                const float    hbf = __uint_as_float(c1 << 16);
                const float    lo  = h - hbf;
                const unsigned c2  = cvt_pk_bf16(h, lo);             // (bf(h), bf(lo))
                *reinterpret_cast<unsigned*>(wp + woff[c][i]) = c2;
            }
        }
        __syncthreads();
        p ^= 1;
    }

    // ---- epilogue: out[r] = sum_j Who[j]*h[r][j] + b_ho ----
    #pragma unroll
    for (int c = 0; c < 2; ++c) {
        #pragma unroll
        for (int i = 0; i < 4; ++i) {
            float v = who[c] * hv[c][i];
            v += __shfl_xor(v, 1);
            v += __shfl_xor(v, 2);
            v += __shfl_xor(v, 4);
            v += __shfl_xor(v, 8);     // reduce over the 16 cols of the tile
            if (l15 == 0) red[g * 4 + i][2 * w + c] = v;
        }
    }
    __syncthreads();
    if (tid < BM) {
        float s = b_ho[0];
        #pragma unroll
        for (int q = 0; q < 8; ++q) s += red[tid][q];
        out[B0 + tid] = s;
    }
}

extern "C" void kernel_launch(void* const* d_in, const int* in_sizes, int n_in,
                              void* d_out, int out_size, void* d_ws, size_t ws_size,
                              hipStream_t stream)
{
    (void)in_sizes; (void)n_in; (void)out_size; (void)d_ws; (void)ws_size;
    const float* x    = (const float*)d_in[0];
    const float* W_ih = (const float*)d_in[1];
    const float* b_ih = (const float*)d_in[2];
    const float* W_ho = (const float*)d_in[3];
    const float* b_ho = (const float*)d_in[4];
    float* out = (float*)d_out;

    dim3 grid(BATCH / BM);     // 256 blocks = 1 per CU
    dim3 block(THREADS);
    elman_mfma3<<<grid, block, 0, stream>>>(x, W_ih, b_ih, W_ho, b_ho, out);
}